// Round 1
// baseline (319.428 us; speedup 1.0000x reference)
//
#include <hip/hip_runtime.h>

#define BB 16
#define TT 144
#define TP1 145
#define HWP 16384
#define HW4 4096
#define LL 6

// ---- workspace layout (bytes) ----
static const size_t OFF_A     = 0;                 // B*HW f32  = 1,048,576
static const size_t OFF_M     = 1048576;           // B*HW f32
static const size_t OFF_U     = 2097152;           // B*HW f32
static const size_t OFF_V     = 3145728;           // B*HW f32
static const size_t OFF_ERR   = 4194304;           // B*145 f64 (18,560 B, reserve 32K)
static const size_t OFF_USED  = 4227072;           // B*145 i32 (reserve 16K)
static const size_t OFF_SEL   = 4243456;           // B i32 (reserve 16K)
static const size_t OFF_BELOW = 4259840;           // B*T*HW f32 = 150,994,944
static const size_t WS_FULL   = OFF_BELOW + 150994944ull;

__global__ void k_init(float* A, float* M, int* used) {
    int i = blockIdx.x * blockDim.x + threadIdx.x;
    if (i < BB * HWP) { A[i] = 0.f; M[i] = 1.f; }
    if (i < BB * TP1) used[i] = 0;
}

__global__ void k_below(const float4* __restrict__ t, const float4* __restrict__ m,
                        const float4* __restrict__ bg, float4* __restrict__ below, int n4) {
    int i = blockIdx.x * blockDim.x + threadIdx.x;
    if (i >= n4) return;
    int p = i % HW4;
    float4 tv = t[i], mv = m[i], bv = bg[p];
    float4 o;
    o.x = tv.x * mv.x + bv.x * (1.f - mv.x);
    o.y = tv.y * mv.y + bv.y * (1.f - mv.y);
    o.z = tv.z * mv.z + bv.z * (1.f - mv.z);
    o.w = tv.w * mv.w + bv.w * (1.f - mv.w);
    below[i] = o;
}

__global__ void k_uv(const float* __restrict__ x, const float* __restrict__ A,
                     const float* __restrict__ M, float* __restrict__ u, float* __restrict__ v) {
    int i = blockIdx.x * blockDim.x + threadIdx.x;
    if (i >= BB * HWP) return;
    float r = x[i] - A[i];
    float mp = M[i];
    u[i] = r * mp;
    v[i] = mp * mp;
}

// err[b][t] = sum_p ( v*w^2 - 2*u*w ),  w = below_t   (constant mean(r^2) dropped; argmin-equivalent)
template <int MODE>  // 0: read precomputed below; 1: compute below on the fly
__global__ void k_err(const float4* __restrict__ below,
                      const float4* __restrict__ temps, const float4* __restrict__ masks,
                      const float4* __restrict__ bg,
                      const float4* __restrict__ u, const float4* __restrict__ v,
                      double* __restrict__ err) {
    const int t = blockIdx.x;   // 0..144
    const int b = blockIdx.y;   // 0..15
    const int tid = threadIdx.x;
    const float4* ub = u + (size_t)b * HW4;
    const float4* vb = v + (size_t)b * HW4;
    double s = 0.0;
    if (t == 0) {
        // empty template: w = 5 everywhere -> s = 25*sum(v) - 10*sum(u)
        for (int j = tid; j < HW4; j += 256) {
            float4 uu = ub[j], vv = vb[j];
            s += 25.0 * ((double)vv.x + vv.y + vv.z + vv.w)
               - 10.0 * ((double)uu.x + uu.y + uu.z + uu.w);
        }
    } else if (MODE == 0) {
        const float4* wb = below + ((size_t)(b * TT + t - 1)) * HW4;
        for (int j = tid; j < HW4; j += 256) {
            float4 w = wb[j], uu = ub[j], vv = vb[j];
            s += (double)w.x * ((double)vv.x * w.x - 2.0 * uu.x);
            s += (double)w.y * ((double)vv.y * w.y - 2.0 * uu.y);
            s += (double)w.z * ((double)vv.z * w.z - 2.0 * uu.z);
            s += (double)w.w * ((double)vv.w * w.w - 2.0 * uu.w);
        }
    } else {
        const float4* tb = temps + ((size_t)(b * TT + t - 1)) * HW4;
        const float4* mb = masks + ((size_t)(b * TT + t - 1)) * HW4;
        for (int j = tid; j < HW4; j += 256) {
            float4 tv = tb[j], mv = mb[j], bv = bg[j], uu = ub[j], vv = vb[j];
            float4 w;
            w.x = tv.x * mv.x + bv.x * (1.f - mv.x);
            w.y = tv.y * mv.y + bv.y * (1.f - mv.y);
            w.z = tv.z * mv.z + bv.z * (1.f - mv.z);
            w.w = tv.w * mv.w + bv.w * (1.f - mv.w);
            s += (double)w.x * ((double)vv.x * w.x - 2.0 * uu.x);
            s += (double)w.y * ((double)vv.y * w.y - 2.0 * uu.y);
            s += (double)w.z * ((double)vv.z * w.z - 2.0 * uu.z);
            s += (double)w.w * ((double)vv.w * w.w - 2.0 * uu.w);
        }
    }
    // wave (64) shuffle reduce, then cross-wave via LDS
    for (int off = 32; off; off >>= 1) s += __shfl_down(s, off);
    __shared__ double sm[4];
    if ((tid & 63) == 0) sm[tid >> 6] = s;
    __syncthreads();
    if (tid == 0) err[(size_t)b * TP1 + t] = sm[0] + sm[1] + sm[2] + sm[3];
}

__global__ void k_argmin(const double* __restrict__ err, int* __restrict__ used,
                         int* __restrict__ sel, float* __restrict__ out_ids, int l) {
    const int b = blockIdx.x;
    const int tid = threadIdx.x;  // 64 threads = 1 wave
    double best = 1e300;
    int bi = TP1;
    for (int t = tid; t < TP1; t += 64) {
        double e = used[b * TP1 + t] ? 1e300 : err[(size_t)b * TP1 + t];
        if (e < best || (e == best && t < bi)) { best = e; bi = t; }
    }
    for (int off = 32; off; off >>= 1) {
        double oe = __shfl_down(best, off);
        int    oi = __shfl_down(bi, off);
        if (oe < best || (oe == best && oi < bi)) { best = oe; bi = oi; }
    }
    if (tid == 0) {
        sel[b] = bi;
        if (bi != 0) used[b * TP1 + bi] = 1;
        out_ids[b * LL + l] = (float)bi;
    }
}

__global__ void k_update(const float4* __restrict__ temps, const float4* __restrict__ masks,
                         const int* __restrict__ sel, float4* __restrict__ A, float4* __restrict__ M,
                         float4* __restrict__ out_obj, float4* __restrict__ out_msk, int l) {
    int gid = blockIdx.x * blockDim.x + threadIdx.x;  // over B*HW/4
    if (gid >= BB * HW4) return;
    int b = gid >> 12;       // /4096
    int p = gid & (HW4 - 1);
    int id = sel[b];
    float4 st, sm;
    if (id == 0) {
        st = make_float4(5.f, 5.f, 5.f, 5.f);
        sm = make_float4(1.f, 1.f, 1.f, 1.f);
    } else {
        size_t base = ((size_t)(b * TT + id - 1)) * HW4 + p;
        st = temps[base];
        sm = masks[base];
    }
    float4 a = A[gid], mp = M[gid];
    a.x += mp.x * st.x * sm.x;  mp.x *= (1.f - sm.x);
    a.y += mp.y * st.y * sm.y;  mp.y *= (1.f - sm.y);
    a.z += mp.z * st.z * sm.z;  mp.z *= (1.f - sm.z);
    a.w += mp.w * st.w * sm.w;  mp.w *= (1.f - sm.w);
    A[gid] = a;
    M[gid] = mp;
    size_t ob = ((size_t)(b * LL + l)) * HW4 + p;
    out_obj[ob] = st;
    out_msk[ob] = sm;
}

__global__ void k_compose(const float4* __restrict__ bg, const float4* __restrict__ obj,
                          const float4* __restrict__ msk, float4* __restrict__ rec) {
    int gid = blockIdx.x * blockDim.x + threadIdx.x;  // over B*HW/4
    if (gid >= BB * HW4) return;
    int b = gid >> 12;
    int p = gid & (HW4 - 1);
    float4 r = bg[p];
    for (int i = LL - 1; i >= 0; --i) {  // paint last-selected first; first-selected ends on top
        size_t ob = ((size_t)(b * LL + i)) * HW4 + p;
        float4 o = obj[ob], m = msk[ob];
        r.x = o.x * m.x + r.x * (1.f - m.x);
        r.y = o.y * m.y + r.y * (1.f - m.y);
        r.z = o.z * m.z + r.z * (1.f - m.z);
        r.w = o.w * m.w + r.w * (1.f - m.w);
    }
    rec[gid] = r;
}

extern "C" void kernel_launch(void* const* d_in, const int* in_sizes, int n_in,
                              void* d_out, int out_size, void* d_ws, size_t ws_size,
                              hipStream_t stream) {
    const float* x     = (const float*)d_in[0];
    const float* temps = (const float*)d_in[1];
    const float* masks = (const float*)d_in[2];
    const float* bg    = (const float*)d_in[3];

    float* out      = (float*)d_out;
    float* out_rec  = out;                              // B*HW          = 262144
    float* out_obj  = out + 262144;                     // B*L*HW        = 1572864
    float* out_msk  = out + 262144 + 1572864;           // B*L*HW
    float* out_ids  = out + 262144 + 2 * 1572864;       // B*L           = 96

    char* ws = (char*)d_ws;
    float*  A     = (float*)(ws + OFF_A);
    float*  M     = (float*)(ws + OFF_M);
    float*  u     = (float*)(ws + OFF_U);
    float*  v     = (float*)(ws + OFF_V);
    double* err   = (double*)(ws + OFF_ERR);
    int*    used  = (int*)(ws + OFF_USED);
    int*    sel   = (int*)(ws + OFF_SEL);
    float*  below = (float*)(ws + OFF_BELOW);

    const bool full = (ws_size >= WS_FULL);

    k_init<<<(BB * HWP + 255) / 256, 256, 0, stream>>>(A, M, used);

    if (full) {
        int n4 = BB * TT * HW4;  // 9,437,184
        k_below<<<(n4 + 255) / 256, 256, 0, stream>>>(
            (const float4*)temps, (const float4*)masks, (const float4*)bg,
            (float4*)below, n4);
    }

    for (int l = 0; l < LL; ++l) {
        k_uv<<<(BB * HWP + 255) / 256, 256, 0, stream>>>(x, A, M, u, v);
        if (full) {
            k_err<0><<<dim3(TP1, BB), 256, 0, stream>>>(
                (const float4*)below, nullptr, nullptr, nullptr,
                (const float4*)u, (const float4*)v, err);
        } else {
            k_err<1><<<dim3(TP1, BB), 256, 0, stream>>>(
                nullptr, (const float4*)temps, (const float4*)masks, (const float4*)bg,
                (const float4*)u, (const float4*)v, err);
        }
        k_argmin<<<BB, 64, 0, stream>>>(err, used, sel, out_ids, l);
        k_update<<<(BB * HW4 + 255) / 256, 256, 0, stream>>>(
            (const float4*)temps, (const float4*)masks, sel,
            (float4*)A, (float4*)M, (float4*)out_obj, (float4*)out_msk, l);
    }

    k_compose<<<(BB * HW4 + 255) / 256, 256, 0, stream>>>(
        (const float4*)bg, (const float4*)out_obj, (const float4*)out_msk, (float4*)out_rec);
}

// Round 2
// 274.633 us; speedup vs baseline: 1.1631x; 1.1631x over previous
//
#include <hip/hip_runtime.h>

#define BB 16
#define TT 144
#define TP1 145
#define HWP 16384
#define HW4 4096
#define LL 6
#define BIGE 1e30

// ---- workspace layout (bytes) ----
static const size_t OFF_A     = 0;                 // B*HW f32
static const size_t OFF_M     = 1048576;           // B*HW f32
static const size_t OFF_U     = 2097152;           // B*HW f32
static const size_t OFF_V     = 3145728;           // B*HW f32
static const size_t OFF_ERR   = 4194304;           // B*145 f64
static const size_t OFF_USED  = 4227072;           // B*145 i32
static const size_t OFF_BELOW = 4259840;           // B*T*HW f32 = 150,994,944
static const size_t WS_FULL   = OFF_BELOW + 150994944ull;

__device__ __forceinline__ double blk_reduce(double s) {
    for (int off = 32; off; off >>= 1) s += __shfl_down(s, off);
    __shared__ double smr[4];
    if ((threadIdx.x & 63) == 0) smr[threadIdx.x >> 6] = s;
    __syncthreads();
    return smr[0] + smr[1] + smr[2] + smr[3];
}

__global__ void k_init(int* used) {
    for (int i = threadIdx.x; i < BB * TP1; i += 256) used[i] = 0;
}

// Materialize below = t*m + bg*(1-m) AND compute step-0 errors (u=x, v=1).
__global__ void k_below_err0(const float4* __restrict__ temps, const float4* __restrict__ masks,
                             const float4* __restrict__ bg, const float4* __restrict__ x,
                             float4* __restrict__ below, double* __restrict__ err) {
    const int t = blockIdx.x, b = blockIdx.y, tid = threadIdx.x;
    const float4* xb = x + (size_t)b * HW4;
    double s = 0.0;
    if (t == 0) {
        // w = 5: term = 25 - 10x per element
        for (int j = tid; j < HW4; j += 256) {
            float4 xv = xb[j];
            s += (double)(100.f - 10.f * (xv.x + xv.y + xv.z + xv.w));
        }
    } else {
        const size_t row = ((size_t)(b * TT + t - 1)) * HW4;
        for (int j = tid; j < HW4; j += 256) {
            float4 tv = temps[row + j], mv = masks[row + j], bv = bg[j], xv = xb[j];
            float4 w;
            w.x = tv.x * mv.x + bv.x * (1.f - mv.x);
            w.y = tv.y * mv.y + bv.y * (1.f - mv.y);
            w.z = tv.z * mv.z + bv.z * (1.f - mv.z);
            w.w = tv.w * mv.w + bv.w * (1.f - mv.w);
            below[row + j] = w;
            float g = w.x * (w.x - 2.f * xv.x) + w.y * (w.y - 2.f * xv.y)
                    + w.z * (w.z - 2.f * xv.z) + w.w * (w.w - 2.f * xv.w);
            s += (double)g;
        }
    }
    double tot = blk_reduce(s);
    if (tid == 0) err[b * TP1 + t] = tot;
}

// err[b][t] = sum_p ( v*w^2 - 2*u*w ); used candidates -> BIG (masked here so argmin needs no used[])
template <int MODE>  // 0: read precomputed below; 1: recompute from temps/masks/bg
__global__ void k_err(const float4* __restrict__ below,
                      const float4* __restrict__ temps, const float4* __restrict__ masks,
                      const float4* __restrict__ bg,
                      const float4* __restrict__ u, const float4* __restrict__ v,
                      const int* __restrict__ used, double* __restrict__ err) {
    const int t = blockIdx.x, b = blockIdx.y, tid = threadIdx.x;
    if (t != 0 && used[b * TP1 + t]) {
        if (tid == 0) err[b * TP1 + t] = BIGE;
        return;
    }
    const float4* ub = u + (size_t)b * HW4;
    const float4* vb = v + (size_t)b * HW4;
    double s = 0.0;
    if (t == 0) {
        for (int j = tid; j < HW4; j += 256) {
            float4 uu = ub[j], vv = vb[j];
            float g = 25.f * (vv.x + vv.y + vv.z + vv.w)
                    - 10.f * (uu.x + uu.y + uu.z + uu.w);
            s += (double)g;
        }
    } else if (MODE == 0) {
        const size_t row = ((size_t)(b * TT + t - 1)) * HW4;
        for (int j = tid; j < HW4; j += 256) {
            float4 w = below[row + j], uu = ub[j], vv = vb[j];
            float g = w.x * (vv.x * w.x - 2.f * uu.x) + w.y * (vv.y * w.y - 2.f * uu.y)
                    + w.z * (vv.z * w.z - 2.f * uu.z) + w.w * (vv.w * w.w - 2.f * uu.w);
            s += (double)g;
        }
    } else {
        const size_t row = ((size_t)(b * TT + t - 1)) * HW4;
        for (int j = tid; j < HW4; j += 256) {
            float4 tv = temps[row + j], mv = masks[row + j], bv = bg[j], uu = ub[j], vv = vb[j];
            float4 w;
            w.x = tv.x * mv.x + bv.x * (1.f - mv.x);
            w.y = tv.y * mv.y + bv.y * (1.f - mv.y);
            w.z = tv.z * mv.z + bv.z * (1.f - mv.z);
            w.w = tv.w * mv.w + bv.w * (1.f - mv.w);
            float g = w.x * (vv.x * w.x - 2.f * uu.x) + w.y * (vv.y * w.y - 2.f * uu.y)
                    + w.z * (vv.z * w.z - 2.f * uu.z) + w.w * (vv.w * w.w - 2.f * uu.w);
            s += (double)g;
        }
    }
    double tot = blk_reduce(s);
    if (tid == 0) err[b * TP1 + t] = tot;
}

// Fused argmin + state update + object emit + (u,v for next step) + used/ids bookkeeping.
template <bool FIRST, bool LAST>
__global__ void k_upd(const float4* __restrict__ temps, const float4* __restrict__ masks,
                      const float4* __restrict__ x, const double* __restrict__ err,
                      int* __restrict__ used, float4* __restrict__ A, float4* __restrict__ M,
                      float4* __restrict__ u, float4* __restrict__ v,
                      float4* __restrict__ out_obj, float4* __restrict__ out_msk,
                      float* __restrict__ out_ids, int l) {
    const int tid = threadIdx.x;
    const int gid = blockIdx.x * 256 + tid;      // over B*HW4 (65536), 256 blocks
    const int b = gid >> 12;
    const int p = gid & (HW4 - 1);
    __shared__ int ssel;
    if (tid < 64) {
        double best = 1e301;
        int bi = TP1;
        for (int t = tid; t < TP1; t += 64) {
            double e = err[b * TP1 + t];
            if (e < best) { best = e; bi = t; }   // t ascending per thread: strict < keeps first
        }
        for (int off = 32; off; off >>= 1) {
            double oe = __shfl_down(best, off);
            int    oi = __shfl_down(bi, off);
            if (oe < best || (oe == best && oi < bi)) { best = oe; bi = oi; }
        }
        if (tid == 0) ssel = bi;
    }
    __syncthreads();
    const int id = ssel;
    float4 st, sm;
    if (id == 0) {
        st = make_float4(5.f, 5.f, 5.f, 5.f);
        sm = make_float4(1.f, 1.f, 1.f, 1.f);
    } else {
        size_t base = ((size_t)(b * TT + id - 1)) * HW4 + p;
        st = temps[base];
        sm = masks[base];
    }
    float4 a, mp;
    if (FIRST) { a = make_float4(0.f, 0.f, 0.f, 0.f); mp = make_float4(1.f, 1.f, 1.f, 1.f); }
    else       { a = A[gid]; mp = M[gid]; }
    a.x += mp.x * st.x * sm.x;  mp.x *= (1.f - sm.x);
    a.y += mp.y * st.y * sm.y;  mp.y *= (1.f - sm.y);
    a.z += mp.z * st.z * sm.z;  mp.z *= (1.f - sm.z);
    a.w += mp.w * st.w * sm.w;  mp.w *= (1.f - sm.w);
    const size_t ob = ((size_t)(b * LL + l)) * HW4 + p;
    out_obj[ob] = st;
    out_msk[ob] = sm;
    if (!LAST) {
        A[gid] = a; M[gid] = mp;
        float4 xv = x[gid];
        float4 uu, vv;
        uu.x = (xv.x - a.x) * mp.x;  vv.x = mp.x * mp.x;
        uu.y = (xv.y - a.y) * mp.y;  vv.y = mp.y * mp.y;
        uu.z = (xv.z - a.z) * mp.z;  vv.z = mp.z * mp.z;
        uu.w = (xv.w - a.w) * mp.w;  vv.w = mp.w * mp.w;
        u[gid] = uu; v[gid] = vv;
    }
    if ((blockIdx.x & 15) == 0 && tid == 0) {      // one block per batch
        if (id != 0) used[b * TP1 + id] = 1;
        out_ids[b * LL + l] = (float)id;
    }
}

// Bitwise-exact dead-leaves painting (same op order as reference _compose).
__global__ void k_compose(const float4* __restrict__ bg, const float4* __restrict__ obj,
                          const float4* __restrict__ msk, float4* __restrict__ rec) {
    int gid = blockIdx.x * blockDim.x + threadIdx.x;
    if (gid >= BB * HW4) return;
    int b = gid >> 12;
    int p = gid & (HW4 - 1);
    float4 r = bg[p];
    for (int i = LL - 1; i >= 0; --i) {
        size_t ob = ((size_t)(b * LL + i)) * HW4 + p;
        float4 o = obj[ob], m = msk[ob];
        r.x = o.x * m.x + r.x * (1.f - m.x);
        r.y = o.y * m.y + r.y * (1.f - m.y);
        r.z = o.z * m.z + r.z * (1.f - m.z);
        r.w = o.w * m.w + r.w * (1.f - m.w);
    }
    rec[gid] = r;
}

__global__ void k_uv0(const float4* __restrict__ x, float4* __restrict__ u, float4* __restrict__ v) {
    int gid = blockIdx.x * blockDim.x + threadIdx.x;
    if (gid >= BB * HW4) return;
    u[gid] = x[gid];
    v[gid] = make_float4(1.f, 1.f, 1.f, 1.f);
}

static inline void launch_upd(bool first, bool last,
                              const float4* temps, const float4* masks, const float4* x,
                              const double* err, int* used, float4* A, float4* M,
                              float4* u, float4* v, float4* out_obj, float4* out_msk,
                              float* out_ids, int l, hipStream_t stream) {
    if (first)
        k_upd<true, false><<<256, 256, 0, stream>>>(temps, masks, x, err, used, A, M, u, v, out_obj, out_msk, out_ids, l);
    else if (last)
        k_upd<false, true><<<256, 256, 0, stream>>>(temps, masks, x, err, used, A, M, u, v, out_obj, out_msk, out_ids, l);
    else
        k_upd<false, false><<<256, 256, 0, stream>>>(temps, masks, x, err, used, A, M, u, v, out_obj, out_msk, out_ids, l);
}

extern "C" void kernel_launch(void* const* d_in, const int* in_sizes, int n_in,
                              void* d_out, int out_size, void* d_ws, size_t ws_size,
                              hipStream_t stream) {
    const float4* x     = (const float4*)d_in[0];
    const float4* temps = (const float4*)d_in[1];
    const float4* masks = (const float4*)d_in[2];
    const float4* bg    = (const float4*)d_in[3];

    float* out      = (float*)d_out;
    float4* out_rec = (float4*)out;                           // B*HW
    float4* out_obj = (float4*)(out + 262144);                // B*L*HW
    float4* out_msk = (float4*)(out + 262144 + 1572864);      // B*L*HW
    float*  out_ids = out + 262144 + 2 * 1572864;             // B*L

    char* ws = (char*)d_ws;
    float4* A     = (float4*)(ws + OFF_A);
    float4* M     = (float4*)(ws + OFF_M);
    float4* u     = (float4*)(ws + OFF_U);
    float4* v     = (float4*)(ws + OFF_V);
    double* err   = (double*)(ws + OFF_ERR);
    int*    used  = (int*)(ws + OFF_USED);
    float4* below = (float4*)(ws + OFF_BELOW);

    const bool full = (ws_size >= WS_FULL);

    k_init<<<1, 256, 0, stream>>>(used);

    if (full) {
        k_below_err0<<<dim3(TP1, BB), 256, 0, stream>>>(temps, masks, bg, x, below, err);
        for (int l = 0; l < LL; ++l) {
            launch_upd(l == 0, l == LL - 1, temps, masks, x, err, used, A, M, u, v,
                       out_obj, out_msk, out_ids, l, stream);
            if (l < LL - 1)
                k_err<0><<<dim3(TP1, BB), 256, 0, stream>>>(
                    below, nullptr, nullptr, nullptr, u, v, used, err);
        }
    } else {
        k_uv0<<<(BB * HW4 + 255) / 256, 256, 0, stream>>>(x, u, v);
        for (int l = 0; l < LL; ++l) {
            k_err<1><<<dim3(TP1, BB), 256, 0, stream>>>(
                nullptr, temps, masks, bg, u, v, used, err);
            launch_upd(l == 0, l == LL - 1, temps, masks, x, err, used, A, M, u, v,
                       out_obj, out_msk, out_ids, l, stream);
        }
    }

    k_compose<<<(BB * HW4 + 255) / 256, 256, 0, stream>>>(bg, out_obj, out_msk, out_rec);
}

// Round 3
// 258.398 us; speedup vs baseline: 1.2362x; 1.0628x over previous
//
#include <hip/hip_runtime.h>

#define BB 16
#define TT 144
#define TP1 145
#define HWP 16384
#define HW4 4096
#define LL 6
#define BIGE 1e30

typedef float f4 __attribute__((ext_vector_type(4)));

// ---- workspace layout (bytes) ----
static const size_t OFF_A     = 0;                 // B*HW f32
static const size_t OFF_M     = 1048576;           // B*HW f32
static const size_t OFF_U     = 2097152;           // B*HW f32
static const size_t OFF_V     = 3145728;           // B*HW f32
static const size_t OFF_ERR   = 4194304;           // B*145 f64
static const size_t OFF_USED  = 4227072;           // B*145 i32
static const size_t OFF_BELOW = 4259840;           // B*T*HW f32 = 150,994,944
static const size_t WS_FULL   = OFF_BELOW + 150994944ull;

__device__ __forceinline__ float hsum(f4 v) { return ((v.x + v.y) + v.z) + v.w; }

__device__ __forceinline__ double blk_reduce(double s) {
    for (int off = 32; off; off >>= 1) s += __shfl_down(s, off);
    __shared__ double smr[4];
    if ((threadIdx.x & 63) == 0) smr[threadIdx.x >> 6] = s;
    __syncthreads();
    return smr[0] + smr[1] + smr[2] + smr[3];
}

// Materialize below = t*m + bg*(1-m), compute step-0 errors (u=x, v=1), zero used[].
// temps/masks are read exactly once in the whole op -> non-temporal (keep L3 for `below`).
__global__ void k_below_err0(const f4* __restrict__ temps, const f4* __restrict__ masks,
                             const f4* __restrict__ bg, const f4* __restrict__ x,
                             f4* __restrict__ below, double* __restrict__ err,
                             int* __restrict__ used) {
    const int t = blockIdx.x, b = blockIdx.y, tid = threadIdx.x;
    const f4* xb = x + (size_t)b * HW4;
    double s = 0.0;
    if (t == 0) {
        if (tid < TP1) used[b * TP1 + tid] = 0;
        for (int j = tid; j < HW4; j += 256) {
            f4 xv = xb[j];
            s += (double)(100.f - 10.f * hsum(xv));
        }
    } else {
        const size_t row = ((size_t)(b * TT + t - 1)) * HW4;
        for (int j = tid; j < HW4; j += 256) {
            f4 tv = __builtin_nontemporal_load(&temps[row + j]);
            f4 mv = __builtin_nontemporal_load(&masks[row + j]);
            f4 bv = bg[j], xv = xb[j];
            f4 w = tv * mv + bv * (1.f - mv);
            below[row + j] = w;
            f4 g = w * (w - 2.f * xv);
            s += (double)hsum(g);
        }
    }
    double tot = blk_reduce(s);
    if (tid == 0) err[b * TP1 + t] = tot;
}

// err[b][t] = sum_p ( v*w^2 - 2*u*w ); used candidates -> BIG
template <int MODE>  // 0: read precomputed below; 1: recompute from temps/masks/bg
__global__ void k_err(const f4* __restrict__ below,
                      const f4* __restrict__ temps, const f4* __restrict__ masks,
                      const f4* __restrict__ bg,
                      const f4* __restrict__ u, const f4* __restrict__ v,
                      const int* __restrict__ used, double* __restrict__ err) {
    const int t = blockIdx.x, b = blockIdx.y, tid = threadIdx.x;
    if (t != 0 && used[b * TP1 + t]) {
        if (tid == 0) err[b * TP1 + t] = BIGE;
        return;
    }
    const f4* ub = u + (size_t)b * HW4;
    const f4* vb = v + (size_t)b * HW4;
    double s = 0.0;
    if (t == 0) {
        for (int j = tid; j < HW4; j += 256) {
            f4 uu = ub[j], vv = vb[j];
            float g = 25.f * hsum(vv) - 10.f * hsum(uu);
            s += (double)g;
        }
    } else if (MODE == 0) {
        const size_t row = ((size_t)(b * TT + t - 1)) * HW4;
        for (int j = tid; j < HW4; j += 256) {
            f4 w = below[row + j], uu = ub[j], vv = vb[j];
            f4 g = w * (vv * w - 2.f * uu);
            s += (double)hsum(g);
        }
    } else {
        const size_t row = ((size_t)(b * TT + t - 1)) * HW4;
        for (int j = tid; j < HW4; j += 256) {
            f4 tv = temps[row + j], mv = masks[row + j], bv = bg[j];
            f4 uu = ub[j], vv = vb[j];
            f4 w = tv * mv + bv * (1.f - mv);
            f4 g = w * (vv * w - 2.f * uu);
            s += (double)hsum(g);
        }
    }
    double tot = blk_reduce(s);
    if (tid == 0) err[b * TP1 + t] = tot;
}

// Fused argmin + state update + object emit + (u,v for next step) + bookkeeping.
// LAST step also emits recons = A_L + M_L * bg  (affine dead-leaves identity).
template <bool FIRST, bool LAST>
__global__ void k_upd(const f4* __restrict__ temps, const f4* __restrict__ masks,
                      const f4* __restrict__ x, const f4* __restrict__ bg,
                      const double* __restrict__ err,
                      int* __restrict__ used, f4* __restrict__ A, f4* __restrict__ M,
                      f4* __restrict__ u, f4* __restrict__ v,
                      f4* __restrict__ out_obj, f4* __restrict__ out_msk,
                      f4* __restrict__ out_rec, float* __restrict__ out_ids, int l) {
    const int tid = threadIdx.x;
    const int gid = blockIdx.x * 256 + tid;      // over B*HW4 (65536), 256 blocks
    const int b = gid >> 12;
    const int p = gid & (HW4 - 1);
    __shared__ int ssel;
    if (tid < 64) {
        double best = 1e301;
        int bi = TP1;
        for (int t = tid; t < TP1; t += 64) {
            double e = err[b * TP1 + t];
            if (e < best) { best = e; bi = t; }   // t ascending per thread: strict < keeps first
        }
        for (int off = 32; off; off >>= 1) {
            double oe = __shfl_down(best, off);
            int    oi = __shfl_down(bi, off);
            if (oe < best || (oe == best && oi < bi)) { best = oe; bi = oi; }
        }
        if (tid == 0) ssel = bi;
    }
    __syncthreads();
    const int id = ssel;
    f4 st, sm;
    if (id == 0) {
        st = (f4){5.f, 5.f, 5.f, 5.f};
        sm = (f4){1.f, 1.f, 1.f, 1.f};
    } else {
        size_t base = ((size_t)(b * TT + id - 1)) * HW4 + p;
        st = temps[base];
        sm = masks[base];
    }
    f4 a, mp;
    if (FIRST) { a = (f4){0.f, 0.f, 0.f, 0.f}; mp = (f4){1.f, 1.f, 1.f, 1.f}; }
    else       { a = A[gid]; mp = M[gid]; }
    a = a + mp * st * sm;
    mp = mp * (1.f - sm);
    const size_t ob = ((size_t)(b * LL + l)) * HW4 + p;
    out_obj[ob] = st;
    out_msk[ob] = sm;
    if (LAST) {
        out_rec[gid] = a + mp * bg[p];
    } else {
        A[gid] = a; M[gid] = mp;
        f4 xv = x[gid];
        u[gid] = (xv - a) * mp;
        v[gid] = mp * mp;
    }
    if ((blockIdx.x & 15) == 0 && tid == 0) {      // one block per batch
        if (id != 0) used[b * TP1 + id] = 1;
        out_ids[b * LL + l] = (float)id;
    }
}

// Fallback-path init: u=x, v=1, used=0.
__global__ void k_uv0(const f4* __restrict__ x, f4* __restrict__ u, f4* __restrict__ v,
                      int* __restrict__ used) {
    int gid = blockIdx.x * blockDim.x + threadIdx.x;
    if (gid < BB * TP1) used[gid] = 0;
    if (gid >= BB * HW4) return;
    u[gid] = x[gid];
    v[gid] = (f4){1.f, 1.f, 1.f, 1.f};
}

static inline void launch_upd(bool first, bool last,
                              const f4* temps, const f4* masks, const f4* x, const f4* bg,
                              const double* err, int* used, f4* A, f4* M,
                              f4* u, f4* v, f4* out_obj, f4* out_msk, f4* out_rec,
                              float* out_ids, int l, hipStream_t stream) {
    if (first)
        k_upd<true, false><<<256, 256, 0, stream>>>(temps, masks, x, bg, err, used, A, M, u, v, out_obj, out_msk, out_rec, out_ids, l);
    else if (last)
        k_upd<false, true><<<256, 256, 0, stream>>>(temps, masks, x, bg, err, used, A, M, u, v, out_obj, out_msk, out_rec, out_ids, l);
    else
        k_upd<false, false><<<256, 256, 0, stream>>>(temps, masks, x, bg, err, used, A, M, u, v, out_obj, out_msk, out_rec, out_ids, l);
}

extern "C" void kernel_launch(void* const* d_in, const int* in_sizes, int n_in,
                              void* d_out, int out_size, void* d_ws, size_t ws_size,
                              hipStream_t stream) {
    const f4* x     = (const f4*)d_in[0];
    const f4* temps = (const f4*)d_in[1];
    const f4* masks = (const f4*)d_in[2];
    const f4* bg    = (const f4*)d_in[3];

    float* out      = (float*)d_out;
    f4*    out_rec  = (f4*)out;                           // B*HW
    f4*    out_obj  = (f4*)(out + 262144);                // B*L*HW
    f4*    out_msk  = (f4*)(out + 262144 + 1572864);      // B*L*HW
    float* out_ids  = out + 262144 + 2 * 1572864;         // B*L

    char* ws = (char*)d_ws;
    f4*     A     = (f4*)(ws + OFF_A);
    f4*     M     = (f4*)(ws + OFF_M);
    f4*     u     = (f4*)(ws + OFF_U);
    f4*     v     = (f4*)(ws + OFF_V);
    double* err   = (double*)(ws + OFF_ERR);
    int*    used  = (int*)(ws + OFF_USED);
    f4*     below = (f4*)(ws + OFF_BELOW);

    const bool full = (ws_size >= WS_FULL);

    if (full) {
        k_below_err0<<<dim3(TP1, BB), 256, 0, stream>>>(temps, masks, bg, x, below, err, used);
        for (int l = 0; l < LL; ++l) {
            launch_upd(l == 0, l == LL - 1, temps, masks, x, bg, err, used, A, M, u, v,
                       out_obj, out_msk, out_rec, out_ids, l, stream);
            if (l < LL - 1)
                k_err<0><<<dim3(TP1, BB), 256, 0, stream>>>(
                    below, nullptr, nullptr, nullptr, u, v, used, err);
        }
    } else {
        k_uv0<<<(BB * HW4 + 255) / 256, 256, 0, stream>>>(x, u, v, used);
        for (int l = 0; l < LL; ++l) {
            k_err<1><<<dim3(TP1, BB), 256, 0, stream>>>(
                nullptr, temps, masks, bg, u, v, used, err);
            launch_upd(l == 0, l == LL - 1, temps, masks, x, bg, err, used, A, M, u, v,
                       out_obj, out_msk, out_rec, out_ids, l, stream);
        }
    }
}